// Round 4
// baseline (888.589 us; speedup 1.0000x reference)
//
#include <hip/hip_runtime.h>
#include <hip/hip_bf16.h>

// Problem constants
#define BB_ 2
#define SS_ 2048
#define DD_ 512
#define HH_ 8
#define DKK_ 64

typedef float fvec4 __attribute__((ext_vector_type(4)));

// ---------------------------------------------------------------------------
// Kernel 1: projection GEMM.  C[z][S][DK] = X[b][S][D] @ W[(h)][D][DK]
// headed=1: z = h*B + b (per-head W);  headed=0: z = b (shared W)
// BM=64, BN=64(=DK), BK=16, 256 threads, 4x4 micro-tile.
// ---------------------------------------------------------------------------
__global__ __launch_bounds__(256) void proj_gemm(
    const float* __restrict__ X, const float* __restrict__ W,
    float* __restrict__ Y, int headed)
{
    const int z = blockIdx.z;
    const int b = headed ? (z % BB_) : z;
    const float* Ab = X + (size_t)b * SS_ * DD_;
    const float* Wb = W + (headed ? (size_t)(z / BB_) * DD_ * DKK_ : (size_t)0);
    float* Cb = Y + (size_t)z * SS_ * DKK_;
    const int row0 = blockIdx.x * 64;

    __shared__ __align__(16) float As[16][64];   // [k][m] transposed
    __shared__ __align__(16) float Bs[16][64];   // [k][n]

    const int tid = threadIdx.x;
    const int tr = tid >> 4;       // 0..15 -> rows tr*4..+3
    const int tc = tid & 15;       // 0..15 -> cols tc*4..+3

    float acc[4][4];
#pragma unroll
    for (int i = 0; i < 4; ++i)
#pragma unroll
        for (int j = 0; j < 4; ++j) acc[i][j] = 0.f;

    for (int k0 = 0; k0 < DD_; k0 += 16) {
        {
            const int ar = tid >> 2;           // 0..63
            const int ak = (tid & 3) << 2;     // 0,4,8,12
            float4 av = *(const float4*)(Ab + (size_t)(row0 + ar) * DD_ + k0 + ak);
            As[ak + 0][ar] = av.x; As[ak + 1][ar] = av.y;
            As[ak + 2][ar] = av.z; As[ak + 3][ar] = av.w;
            const int bk = tid >> 4;           // 0..15
            const int bn = (tid & 15) << 2;    // 0..60
            *(float4*)(&Bs[bk][bn]) = *(const float4*)(Wb + (size_t)(k0 + bk) * DKK_ + bn);
        }
        __syncthreads();
#pragma unroll
        for (int k = 0; k < 16; ++k) {
            float4 a  = *(const float4*)(&As[k][tr << 2]);
            float4 bv = *(const float4*)(&Bs[k][tc << 2]);
            acc[0][0] += a.x * bv.x; acc[0][1] += a.x * bv.y; acc[0][2] += a.x * bv.z; acc[0][3] += a.x * bv.w;
            acc[1][0] += a.y * bv.x; acc[1][1] += a.y * bv.y; acc[1][2] += a.y * bv.z; acc[1][3] += a.y * bv.w;
            acc[2][0] += a.z * bv.x; acc[2][1] += a.z * bv.y; acc[2][2] += a.z * bv.z; acc[2][3] += a.z * bv.w;
            acc[3][0] += a.w * bv.x; acc[3][1] += a.w * bv.y; acc[3][2] += a.w * bv.z; acc[3][3] += a.w * bv.w;
        }
        __syncthreads();
    }
#pragma unroll
    for (int i = 0; i < 4; ++i) {
        float4 o = make_float4(acc[i][0], acc[i][1], acc[i][2], acc[i][3]);
        *(float4*)(Cb + (size_t)(row0 + (tr << 2) + i) * DKK_ + (tc << 2)) = o;
    }
}

// ---------------------------------------------------------------------------
// Kernel 2: fused attention per (h, b, 16-row tile).
//   scores (LDS f32, padded) -> softmax (max/exp/sum) -> write attn ->
//   PV with vh staged in LDS -> write heads.
// 512 threads (8 waves), ~152 KB LDS, 1 block/CU.
// ---------------------------------------------------------------------------
#define PS_ 2052   // padded row stride for score tile (2048 + 4)

#define SCORES_STEP(QBASE, AA, BV)                                          \
    do {                                                                     \
        float4 q0 = *(const float4*)((QBASE));                               \
        float4 q1 = *(const float4*)((QBASE) + 4);                           \
        float4 q2 = *(const float4*)((QBASE) + 8);                           \
        float4 q3 = *(const float4*)((QBASE) + 12);                          \
        acc0[0]  += q0.x * (AA); acc1[0]  += q0.x * (BV);                    \
        acc0[1]  += q0.y * (AA); acc1[1]  += q0.y * (BV);                    \
        acc0[2]  += q0.z * (AA); acc1[2]  += q0.z * (BV);                    \
        acc0[3]  += q0.w * (AA); acc1[3]  += q0.w * (BV);                    \
        acc0[4]  += q1.x * (AA); acc1[4]  += q1.x * (BV);                    \
        acc0[5]  += q1.y * (AA); acc1[5]  += q1.y * (BV);                    \
        acc0[6]  += q1.z * (AA); acc1[6]  += q1.z * (BV);                    \
        acc0[7]  += q1.w * (AA); acc1[7]  += q1.w * (BV);                    \
        acc0[8]  += q2.x * (AA); acc1[8]  += q2.x * (BV);                    \
        acc0[9]  += q2.y * (AA); acc1[9]  += q2.y * (BV);                    \
        acc0[10] += q2.z * (AA); acc1[10] += q2.z * (BV);                    \
        acc0[11] += q2.w * (AA); acc1[11] += q2.w * (BV);                    \
        acc0[12] += q3.x * (AA); acc1[12] += q3.x * (BV);                    \
        acc0[13] += q3.y * (AA); acc1[13] += q3.y * (BV);                    \
        acc0[14] += q3.z * (AA); acc1[14] += q3.z * (BV);                    \
        acc0[15] += q3.w * (AA); acc1[15] += q3.w * (BV);                    \
    } while (0)

__global__ __launch_bounds__(512, 2) void attn_fused(
    const float* __restrict__ qh,     // [H,B,S,DK]
    const float* __restrict__ kh,     // [H,B,S,DK]
    const float* __restrict__ vh,     // [B,S,DK]
    const float* __restrict__ scale_p,
    float* __restrict__ attn_out,     // [H,B,S,S]
    float* __restrict__ heads)        // [H,B,S,DK]
{
    __shared__ __align__(16) float p[16 * PS_];     // 131,328 B score/exp tile
    __shared__ __align__(16) float qTm[64 * 16];    // q tile transposed [k][r]
    __shared__ __align__(16) float vs[64][64];      // vh tile
    __shared__ float rowl[16];

    const int tid  = threadIdx.x;
    const int bb   = blockIdx.y;
    const int hh   = blockIdx.z;
    const int hb   = hh * BB_ + bb;
    const int row0 = blockIdx.x * 16;

    // ---- stage q tile transposed ----
    if (tid < 256) {
        const int r  = tid >> 4;
        const int k4 = (tid & 15) << 2;
        float4 qv = *(const float4*)(qh + ((size_t)hb * SS_ + row0 + r) * DKK_ + k4);
        qTm[(k4 + 0) * 16 + r] = qv.x;
        qTm[(k4 + 1) * 16 + r] = qv.y;
        qTm[(k4 + 2) * 16 + r] = qv.z;
        qTm[(k4 + 3) * 16 + r] = qv.w;
    }
    __syncthreads();

    // ---- scores: each thread owns 2 kh rows (cols) per pass ----
    const float sc = *scale_p;
    const float* khb = kh + (size_t)hb * SS_ * DKK_;

    for (int pass = 0; pass < 2; ++pass) {
        const int c0 = pass * 1024 + (tid << 1);
        const float* kr0 = khb + (size_t)c0 * DKK_;
        const float* kr1 = kr0 + DKK_;

        float acc0[16], acc1[16];
#pragma unroll
        for (int i = 0; i < 16; ++i) { acc0[i] = 0.f; acc1[i] = 0.f; }

        // software-pipelined over j (4 k's per j)
        float4 a  = *(const float4*)(kr0);
        float4 bv = *(const float4*)(kr1);
        for (int j = 0; j < 16; ++j) {
            float4 an, bn;
            if (j < 15) {
                an = *(const float4*)(kr0 + ((j + 1) << 2));
                bn = *(const float4*)(kr1 + ((j + 1) << 2));
            }
            const float* qrow = &qTm[j << 6];
            SCORES_STEP(qrow,      a.x, bv.x);
            SCORES_STEP(qrow + 16, a.y, bv.y);
            SCORES_STEP(qrow + 32, a.z, bv.z);
            SCORES_STEP(qrow + 48, a.w, bv.w);
            a = an; bv = bn;
        }
#pragma unroll
        for (int rr = 0; rr < 16; ++rr) {
            *(float2*)&p[rr * PS_ + c0] = make_float2(acc0[rr] * sc, acc1[rr] * sc);
        }
    }
    __syncthreads();

    // ---- softmax per row (row r owned by 32-lane group tid>>5) ----
    const int lane = tid & 31;
    const int r    = tid >> 5;           // 0..15
    float* prow = p + r * PS_;

    float m = -3.402823e38f;
#pragma unroll
    for (int i = 0; i < 16; ++i) {
        float4 v = *(const float4*)&prow[(lane << 2) + (i << 7)];
        m = fmaxf(m, fmaxf(fmaxf(v.x, v.y), fmaxf(v.z, v.w)));
    }
#pragma unroll
    for (int off = 16; off; off >>= 1) m = fmaxf(m, __shfl_xor(m, off, 32));

    float l = 0.f;
#pragma unroll
    for (int i = 0; i < 16; ++i) {
        float4 v = *(const float4*)&prow[(lane << 2) + (i << 7)];
        v.x = __expf(v.x - m); v.y = __expf(v.y - m);
        v.z = __expf(v.z - m); v.w = __expf(v.w - m);
        *(float4*)&prow[(lane << 2) + (i << 7)] = v;
        l += v.x + v.y + v.z + v.w;
    }
#pragma unroll
    for (int off = 16; off; off >>= 1) l += __shfl_xor(l, off, 32);
    if (lane == 0) rowl[r] = l;
    const float rcp = 1.0f / l;

    // ---- write normalized attn to global (nontemporal: write-once, 256 MiB) ----
    float* arow = attn_out + (((size_t)hb) * SS_ + (row0 + r)) * SS_;
#pragma unroll
    for (int i = 0; i < 16; ++i) {
        float4 v = *(const float4*)&prow[(lane << 2) + (i << 7)];
        v.x *= rcp; v.y *= rcp; v.z *= rcp; v.w *= rcp;
        fvec4 nv = { v.x, v.y, v.z, v.w };
        __builtin_nontemporal_store(nv, (fvec4*)&arow[(lane << 2) + (i << 7)]);
    }
    __syncthreads();   // p (exp, unnormalized) now fully ready for all waves

    // ---- PV: heads[16][64] = p @ vh, vh tiles staged in LDS ----
    const int kk = tid & 31;             // 2 cols: 2kk, 2kk+1
    const int r8 = (tid >> 5) & 1;       // row half
    const int tg = tid >> 6;             // 0..7 t-subgroup
    const int rb = r8 << 3;
    const float* vhb = vh + (size_t)bb * SS_ * DKK_;

    float pacc[8][2];
#pragma unroll
    for (int i = 0; i < 8; ++i) { pacc[i][0] = 0.f; pacc[i][1] = 0.f; }

    for (int ti = 0; ti < 32; ++ti) {
        {
            const int t  = tid >> 3;
            const int k8 = (tid & 7) << 3;
            const float* src = vhb + (size_t)((ti << 6) + t) * DKK_ + k8;
            *(float4*)&vs[t][k8]     = *(const float4*)(src);
            *(float4*)&vs[t][k8 + 4] = *(const float4*)(src + 4);
        }
        __syncthreads();
#pragma unroll
        for (int ii = 0; ii < 2; ++ii) {
            const int tt = (tg << 3) + (ii << 2);
            const float2 w0 = *(const float2*)&vs[tt + 0][kk << 1];
            const float2 w1 = *(const float2*)&vs[tt + 1][kk << 1];
            const float2 w2 = *(const float2*)&vs[tt + 2][kk << 1];
            const float2 w3 = *(const float2*)&vs[tt + 3][kk << 1];
            const int tglob = (ti << 6) + tt;
#pragma unroll
            for (int rr = 0; rr < 8; ++rr) {
                float4 pv = *(const float4*)&p[(rb + rr) * PS_ + tglob];
                pacc[rr][0] += pv.x * w0.x + pv.y * w1.x + pv.z * w2.x + pv.w * w3.x;
                pacc[rr][1] += pv.x * w0.y + pv.y * w1.y + pv.z * w2.y + pv.w * w3.y;
            }
        }
        __syncthreads();
    }

    // ---- reduce the 8 t-subgroup partials via LDS (alias onto p) ----
    __syncthreads();
    float* red = p;
#pragma unroll
    for (int rr = 0; rr < 8; ++rr) {
        *(float2*)&red[(tid << 4) + (rr << 1)] = make_float2(pacc[rr][0], pacc[rr][1]);
    }
    __syncthreads();
    for (int o = tid; o < 1024; o += 512) {
        const int ro  = o >> 6, kc = o & 63;
        const int r8o = ro >> 3, rro = ro & 7, kko = kc >> 1, cco = kc & 1;
        float s = 0.f;
#pragma unroll
        for (int tg2 = 0; tg2 < 8; ++tg2)
            s += red[(((tg2 << 6) + (r8o << 5) + kko) << 4) + (rro << 1) + cco];
        s *= (1.0f / rowl[ro]);
        heads[(((size_t)hb) * SS_ + row0 + ro) * DKK_ + kc] = s;
    }
}

// ---------------------------------------------------------------------------
// Kernel 3: y = (mean_h heads) @ Wo.   256 threads = 4 rows x 64 cols.
// ---------------------------------------------------------------------------
__global__ __launch_bounds__(256) void head_mean_wo(
    const float* __restrict__ heads, const float* __restrict__ Wo,
    float* __restrict__ y)
{
    __shared__ float ms[4][64];
    const int tid = threadIdx.x;
    const int row = blockIdx.x * 4 + (tid >> 6);   // 0..B*S-1
    const int kk  = tid & 63;

    float s = 0.f;
#pragma unroll
    for (int h = 0; h < HH_; ++h)
        s += heads[((size_t)h * BB_ * SS_ + row) * DKK_ + kk];
    ms[tid >> 6][kk] = s * (1.0f / HH_);
    __syncthreads();

    float acc = 0.f;
#pragma unroll
    for (int k = 0; k < DKK_; ++k)
        acc += ms[tid >> 6][k] * Wo[k * DKK_ + kk];
    y[(size_t)row * DKK_ + kk] = acc;
}

// ---------------------------------------------------------------------------
extern "C" void kernel_launch(void* const* d_in, const int* in_sizes, int n_in,
                              void* d_out, int out_size, void* d_ws, size_t ws_size,
                              hipStream_t stream)
{
    const float* q     = (const float*)d_in[0];
    const float* k     = (const float*)d_in[1];
    const float* v     = (const float*)d_in[2];
    const float* Wq    = (const float*)d_in[3];
    const float* Wk    = (const float*)d_in[4];
    const float* Wv    = (const float*)d_in[5];
    const float* Wo    = (const float*)d_in[6];
    const float* scale = (const float*)d_in[7];

    float* y_out    = (float*)d_out;
    float* attn_out = y_out + (size_t)BB_ * SS_ * DKK_;

    float* ws    = (float*)d_ws;
    float* qh    = ws;                                  // H*B*S*DK = 2,097,152
    float* kh    = qh + (size_t)HH_ * BB_ * SS_ * DKK_; // 2,097,152
    float* vh    = kh + (size_t)HH_ * BB_ * SS_ * DKK_; // B*S*DK = 262,144
    float* heads = vh + (size_t)BB_ * SS_ * DKK_;       // 2,097,152

    proj_gemm<<<dim3(SS_ / 64, 1, HH_ * BB_), 256, 0, stream>>>(q, Wq, qh, 1);
    proj_gemm<<<dim3(SS_ / 64, 1, HH_ * BB_), 256, 0, stream>>>(k, Wk, kh, 1);
    proj_gemm<<<dim3(SS_ / 64, 1, BB_),       256, 0, stream>>>(v, Wv, vh, 0);

    attn_fused<<<dim3(SS_ / 16, BB_, HH_), 512, 0, stream>>>(
        qh, kh, vh, scale, attn_out, heads);

    head_mean_wo<<<dim3(BB_ * SS_ / 4), 256, 0, stream>>>(heads, Wo, y_out);
}

// Round 5
// 555.108 us; speedup vs baseline: 1.6008x; 1.6008x over previous
//
#include <hip/hip_runtime.h>

// Problem constants
#define BB_ 2
#define SS_ 2048
#define DD_ 512
#define HH_ 8
#define DKK_ 64

typedef float  f32x4 __attribute__((ext_vector_type(4)));
typedef short  s16x8 __attribute__((ext_vector_type(8)));
typedef _Float16 h16x8 __attribute__((ext_vector_type(8)));
typedef unsigned short u16x4 __attribute__((ext_vector_type(4)));

__device__ inline unsigned short f2bf(float x) {
    union { float f; unsigned int u; } c; c.f = x;
    unsigned int u = c.u;
    return (unsigned short)((u + 0x7fffu + ((u >> 16) & 1u)) >> 16);
}
__device__ inline float bf2f(unsigned short b) {
    union { unsigned int u; float f; } c; c.u = ((unsigned int)b) << 16;
    return c.f;
}
__device__ inline unsigned short f2h(float x) {
    _Float16 h = (_Float16)x;
    return __builtin_bit_cast(unsigned short, h);
}

// ---------------------------------------------------------------------------
// Kernel 1: projection GEMM (fp32 compute).
// mode=1: per-head W, z=h*B+b; outputs hi/lo bf16 split [z][S][64].
// mode=0: shared W, z=b; output vT fp16 transposed [b][64][S].
// ---------------------------------------------------------------------------
__global__ __launch_bounds__(256) void proj_gemm(
    const float* __restrict__ X, const float* __restrict__ W,
    unsigned short* __restrict__ Ohi, unsigned short* __restrict__ Olo,
    unsigned short* __restrict__ OvT, int mode)
{
    const int z = blockIdx.z;
    const int b = mode ? (z % BB_) : z;
    const float* Ab = X + (size_t)b * SS_ * DD_;
    const float* Wb = W + (mode ? (size_t)(z / BB_) * DD_ * DKK_ : (size_t)0);
    const int row0 = blockIdx.x * 64;

    __shared__ __align__(16) float As[16][64];   // [k][m]
    __shared__ __align__(16) float Bs[16][64];   // [k][n]

    const int tid = threadIdx.x;
    const int tr = tid >> 4;
    const int tc = tid & 15;

    float acc[4][4];
#pragma unroll
    for (int i = 0; i < 4; ++i)
#pragma unroll
        for (int j = 0; j < 4; ++j) acc[i][j] = 0.f;

    for (int k0 = 0; k0 < DD_; k0 += 16) {
        {
            const int ar = tid >> 2;
            const int ak = (tid & 3) << 2;
            float4 av = *(const float4*)(Ab + (size_t)(row0 + ar) * DD_ + k0 + ak);
            As[ak + 0][ar] = av.x; As[ak + 1][ar] = av.y;
            As[ak + 2][ar] = av.z; As[ak + 3][ar] = av.w;
            const int bk = tid >> 4;
            const int bn = (tid & 15) << 2;
            *(float4*)(&Bs[bk][bn]) = *(const float4*)(Wb + (size_t)(k0 + bk) * DKK_ + bn);
        }
        __syncthreads();
#pragma unroll
        for (int k = 0; k < 16; ++k) {
            float4 a  = *(const float4*)(&As[k][tr << 2]);
            float4 bv = *(const float4*)(&Bs[k][tc << 2]);
            acc[0][0] += a.x * bv.x; acc[0][1] += a.x * bv.y; acc[0][2] += a.x * bv.z; acc[0][3] += a.x * bv.w;
            acc[1][0] += a.y * bv.x; acc[1][1] += a.y * bv.y; acc[1][2] += a.y * bv.z; acc[1][3] += a.y * bv.w;
            acc[2][0] += a.z * bv.x; acc[2][1] += a.z * bv.y; acc[2][2] += a.z * bv.z; acc[2][3] += a.z * bv.w;
            acc[3][0] += a.w * bv.x; acc[3][1] += a.w * bv.y; acc[3][2] += a.w * bv.z; acc[3][3] += a.w * bv.w;
        }
        __syncthreads();
    }

    if (mode) {
#pragma unroll
        for (int i = 0; i < 4; ++i) {
            const size_t ro = ((size_t)z * SS_ + row0 + (tr << 2) + i) * DKK_ + (tc << 2);
            u16x4 hv, lv;
#pragma unroll
            for (int jj = 0; jj < 4; ++jj) {
                const float x = acc[i][jj];
                const unsigned short hb = f2bf(x);
                hv[jj] = hb;
                lv[jj] = f2bf(x - bf2f(hb));
            }
            *(u16x4*)(Ohi + ro) = hv;
            *(u16x4*)(Olo + ro) = lv;
        }
    } else {
#pragma unroll
        for (int i = 0; i < 4; ++i)
#pragma unroll
            for (int jj = 0; jj < 4; ++jj)
                OvT[((size_t)z * DKK_ + (tc << 2) + jj) * SS_ + row0 + (tr << 2) + i] = f2h(acc[i][jj]);
    }
}

// ---------------------------------------------------------------------------
// Kernel 2: MFMA fused attention. Block = (h,b,16 q-rows), 512 threads (8 waves).
// Wave w owns score cols [w*256, w*256+256) as 16 MFMA acc tiles (registers).
// QK^T: bf16 2-term split (hh+hl+lh). Softmax in registers + small LDS reduce.
// P -> fp16 LDS tile; PV: f16 MFMA, V from pre-transposed vT (fp16, global/L2).
// ---------------------------------------------------------------------------
__global__ __launch_bounds__(512, 4) void attn_mfma(
    const unsigned short* __restrict__ qhh, const unsigned short* __restrict__ qhl,
    const unsigned short* __restrict__ khh, const unsigned short* __restrict__ khl,
    const unsigned short* __restrict__ vT,
    const float* __restrict__ scale_p,
    float* __restrict__ attn_out,      // [H,B,S,S]
    float* __restrict__ heads)         // [H,B,S,DK]
{
    __shared__ __align__(16) unsigned short pbf[16][2056];  // exp(s-m) fp16, pad 8 -> 8-quad spread
    __shared__ float rmax[16][8];
    __shared__ float rsum[16][8];
    __shared__ float rowl[16];
    __shared__ __align__(16) float pvred[4][64][4];

    const int tid  = threadIdx.x;
    const int w    = tid >> 6;          // wave 0..7
    const int lane = tid & 63;
    const int a16  = lane & 15;         // A-row / B-col / D-col lane map
    const int g    = lane >> 4;         // 0..3
    const int bb   = blockIdx.y;
    const int hh   = blockIdx.z;
    const int hb   = hh * BB_ + bb;
    const int row0 = blockIdx.x * 16;
    const float sc = *scale_p;

    // ---- A-frags: q rows (hi/lo x 2 ksteps), loaded once ----
    const size_t qoff = ((size_t)hb * SS_ + row0 + a16) * DKK_;
    s16x8 qA00 = *(const s16x8*)(qhh + qoff + g * 8);
    s16x8 qA01 = *(const s16x8*)(qhh + qoff + 32 + g * 8);
    s16x8 qA10 = *(const s16x8*)(qhl + qoff + g * 8);
    s16x8 qA11 = *(const s16x8*)(qhl + qoff + 32 + g * 8);

    // ---- scores: 16 n-tiles per wave, 6 MFMA each ----
    const int c0 = w * 256;
    f32x4 acc[16];
#pragma unroll
    for (int nt = 0; nt < 16; ++nt) {
        const size_t koff = ((size_t)hb * SS_ + c0 + nt * 16 + a16) * DKK_;
        s16x8 kB0h = *(const s16x8*)(khh + koff + g * 8);
        s16x8 kB1h = *(const s16x8*)(khh + koff + 32 + g * 8);
        s16x8 kB0l = *(const s16x8*)(khl + koff + g * 8);
        s16x8 kB1l = *(const s16x8*)(khl + koff + 32 + g * 8);
        f32x4 a = {0.f, 0.f, 0.f, 0.f};
        a = __builtin_amdgcn_mfma_f32_16x16x32_bf16(qA00, kB0h, a, 0, 0, 0);
        a = __builtin_amdgcn_mfma_f32_16x16x32_bf16(qA01, kB1h, a, 0, 0, 0);
        a = __builtin_amdgcn_mfma_f32_16x16x32_bf16(qA00, kB0l, a, 0, 0, 0);
        a = __builtin_amdgcn_mfma_f32_16x16x32_bf16(qA01, kB1l, a, 0, 0, 0);
        a = __builtin_amdgcn_mfma_f32_16x16x32_bf16(qA10, kB0h, a, 0, 0, 0);
        a = __builtin_amdgcn_mfma_f32_16x16x32_bf16(qA11, kB1h, a, 0, 0, 0);
        acc[nt] = a * sc;
    }

    // ---- row max: in-register over nt, shfl over the 16-lane group, LDS over waves ----
    float mx[4];
#pragma unroll
    for (int j = 0; j < 4; ++j) {
        float m = acc[0][j];
#pragma unroll
        for (int nt = 1; nt < 16; ++nt) m = fmaxf(m, acc[nt][j]);
        m = fmaxf(m, __shfl_xor(m, 1));
        m = fmaxf(m, __shfl_xor(m, 2));
        m = fmaxf(m, __shfl_xor(m, 4));
        m = fmaxf(m, __shfl_xor(m, 8));
        mx[j] = m;
    }
    if (a16 == 0) {
#pragma unroll
        for (int j = 0; j < 4; ++j) rmax[g * 4 + j][w] = mx[j];
    }
    __syncthreads();
    float mfin[4], sm[4];
#pragma unroll
    for (int j = 0; j < 4; ++j) {
        float m = rmax[g * 4 + j][0];
#pragma unroll
        for (int wv = 1; wv < 8; ++wv) m = fmaxf(m, rmax[g * 4 + j][wv]);
        mfin[j] = m;
        sm[j] = 0.f;
    }

    // ---- exp in registers + row sum ----
#pragma unroll
    for (int nt = 0; nt < 16; ++nt) {
#pragma unroll
        for (int j = 0; j < 4; ++j) {
            const float e = __expf(acc[nt][j] - mfin[j]);
            acc[nt][j] = e;
            sm[j] += e;
        }
    }
#pragma unroll
    for (int j = 0; j < 4; ++j) {
        float s = sm[j];
        s += __shfl_xor(s, 1);
        s += __shfl_xor(s, 2);
        s += __shfl_xor(s, 4);
        s += __shfl_xor(s, 8);
        sm[j] = s;
    }
    if (a16 == 0) {
#pragma unroll
        for (int j = 0; j < 4; ++j) rsum[g * 4 + j][w] = sm[j];
    }
    __syncthreads();
    float rcpL[4];
#pragma unroll
    for (int j = 0; j < 4; ++j) {
        float L = rsum[g * 4 + j][0];
#pragma unroll
        for (int wv = 1; wv < 8; ++wv) L += rsum[g * 4 + j][wv];
        rcpL[j] = 1.0f / L;
        if (w == 0 && a16 == 0) rowl[g * 4 + j] = L;
    }

    // ---- write attn (normalized, nontemporal) + stage P (unnormalized exp) as fp16 ----
    float* abase = attn_out + ((size_t)hb * SS_ + row0) * SS_;
#pragma unroll
    for (int nt = 0; nt < 16; ++nt) {
        const int col = c0 + nt * 16 + a16;
#pragma unroll
        for (int j = 0; j < 4; ++j) {
            const float e = acc[nt][j];
            __builtin_nontemporal_store(e * rcpL[j], abase + (size_t)(g * 4 + j) * SS_ + col);
            pbf[g * 4 + j][col] = f2h(e);
        }
    }
    __syncthreads();   // pbf + rowl ready

    // ---- PV: wave w -> v-col tile (w&3), k-half (w>>2); f16 MFMA ----
    const int nv = w & 3;
    const int kh2 = w >> 2;
    const unsigned short* vb = vT + ((size_t)bb * DKK_ + nv * 16 + a16) * SS_;
    f32x4 pacc = {0.f, 0.f, 0.f, 0.f};
#pragma unroll
    for (int ks = 0; ks < 32; ++ks) {
        const int k0 = kh2 * 1024 + ks * 32 + g * 8;
        h16x8 af = __builtin_bit_cast(h16x8, *(const s16x8*)(&pbf[a16][k0]));
        h16x8 bf = __builtin_bit_cast(h16x8, *(const s16x8*)(vb + k0));
        pacc = __builtin_amdgcn_mfma_f32_16x16x32_f16(af, bf, pacc, 0, 0, 0);
    }

    if (w < 4) {
        *(f32x4*)(&pvred[w][lane][0]) = pacc;
    }
    __syncthreads();
    if (w >= 4) {
        f32x4 o = pacc + *(const f32x4*)(&pvred[w - 4][lane][0]);
#pragma unroll
        for (int j = 0; j < 4; ++j) {
            heads[((size_t)hb * SS_ + row0 + g * 4 + j) * DKK_ + nv * 16 + a16] =
                o[j] / rowl[g * 4 + j];
        }
    }
}

// ---------------------------------------------------------------------------
// Kernel 3: y = (mean_h heads) @ Wo.
// ---------------------------------------------------------------------------
__global__ __launch_bounds__(256) void head_mean_wo(
    const float* __restrict__ heads, const float* __restrict__ Wo,
    float* __restrict__ y)
{
    __shared__ float ms[4][64];
    const int tid = threadIdx.x;
    const int row = blockIdx.x * 4 + (tid >> 6);
    const int kk  = tid & 63;

    float s = 0.f;
#pragma unroll
    for (int h = 0; h < HH_; ++h)
        s += heads[((size_t)h * BB_ * SS_ + row) * DKK_ + kk];
    ms[tid >> 6][kk] = s * (1.0f / HH_);
    __syncthreads();

    float acc = 0.f;
#pragma unroll
    for (int k = 0; k < DKK_; ++k)
        acc += ms[tid >> 6][k] * Wo[k * DKK_ + kk];
    y[(size_t)row * DKK_ + kk] = acc;
}

// ---------------------------------------------------------------------------
extern "C" void kernel_launch(void* const* d_in, const int* in_sizes, int n_in,
                              void* d_out, int out_size, void* d_ws, size_t ws_size,
                              hipStream_t stream)
{
    const float* q     = (const float*)d_in[0];
    const float* k     = (const float*)d_in[1];
    const float* v     = (const float*)d_in[2];
    const float* Wq    = (const float*)d_in[3];
    const float* Wk    = (const float*)d_in[4];
    const float* Wv    = (const float*)d_in[5];
    const float* Wo    = (const float*)d_in[6];
    const float* scale = (const float*)d_in[7];

    float* y_out    = (float*)d_out;
    float* attn_out = y_out + (size_t)BB_ * SS_ * DKK_;

    const size_t NQ = (size_t)HH_ * BB_ * SS_ * DKK_;   // 1,048,576
    unsigned short* qhh = (unsigned short*)d_ws;
    unsigned short* qhl = qhh + NQ;
    unsigned short* khh = qhl + NQ;
    unsigned short* khl = khh + NQ;
    unsigned short* vT  = khl + NQ;                     // B*DK*S = 262,144
    float* heads = (float*)(vT + (size_t)BB_ * DKK_ * SS_);

    proj_gemm<<<dim3(SS_ / 64, 1, HH_ * BB_), 256, 0, stream>>>(q, Wq, qhh, qhl, nullptr, 1);
    proj_gemm<<<dim3(SS_ / 64, 1, HH_ * BB_), 256, 0, stream>>>(k, Wk, khh, khl, nullptr, 1);
    proj_gemm<<<dim3(SS_ / 64, 1, BB_),       256, 0, stream>>>(v, Wv, nullptr, nullptr, vT, 0);

    attn_mfma<<<dim3(SS_ / 16, BB_, HH_), 512, 0, stream>>>(
        qhh, qhl, khh, khl, vT, scale, attn_out, heads);

    head_mean_wo<<<dim3(BB_ * SS_ / 4), 256, 0, stream>>>(heads, Wo, y_out);
}